// Round 9
// baseline (150.093 us; speedup 1.0000x reference)
//
#include <hip/hip_runtime.h>
#include <hip/hip_bf16.h>
#include <stdint.h>

#define MARGIN   0.5f
#define POS_THR  (1.0f - 1e-5f)

typedef __attribute__((ext_vector_type(8))) short  short8;
typedef __attribute__((ext_vector_type(4))) float  f32x4;

#define BM 128
#define BN 128
#define NSLOTS 256       // misc[0..255] partial sums, misc[256] = stale pos
#define MAXN_HIST 8192

// ---------- helpers ----------
__device__ __forceinline__ ushort f2bf_rne(float x) {
  uint32_t u = __float_as_uint(x);
  u += 0x7fffu + ((u >> 16) & 1u);
  return (ushort)(u >> 16);
}

// ---------- prep: convert blocks + ONE setup block (hist -> meta/flags) ----------
__global__ __launch_bounds__(256) void prep_kernel(
    const float* __restrict__ src, ushort* __restrict__ dst,
    const int* __restrict__ target, const int* __restrict__ new_idx,
    int2* __restrict__ metaG, int* __restrict__ flags, float* __restrict__ misc,
    int total8, int n, int npanel, int n_new, int convBlocks) {
  const int tid = threadIdx.x;
  if ((int)blockIdx.x < convBlocks) {
    int i = blockIdx.x * blockDim.x + tid;
    if (i < total8) {
      const float4* s4 = reinterpret_cast<const float4*>(src);
      float4 a = s4[i * 2], b = s4[i * 2 + 1];
      short8 o;
      o[0] = (short)f2bf_rne(a.x); o[1] = (short)f2bf_rne(a.y);
      o[2] = (short)f2bf_rne(a.z); o[3] = (short)f2bf_rne(a.w);
      o[4] = (short)f2bf_rne(b.x); o[5] = (short)f2bf_rne(b.y);
      o[6] = (short)f2bf_rne(b.z); o[7] = (short)f2bf_rne(b.w);
      reinterpret_cast<short8*>(dst)[i] = o;
    }
    return;
  }
  // ---- setup block (n <= MAXN_HIST) ----
  __shared__ int hcnt[MAXN_HIST];
  __shared__ int hflag[MAXN_HIST / BN];
  for (int i = tid; i < n; i += 256) hcnt[i] = 0;
  for (int i = tid; i < npanel; i += 256) hflag[i] = 0;
  __syncthreads();
  for (int i = tid; i < n_new; i += 256) atomicAdd(&hcnt[new_idx[i]], 1);
  __syncthreads();
  for (int i = tid; i < n; i += 256) {
    int c = hcnt[i];
    metaG[i] = make_int2(target[i], __float_as_int((float)c));
    if (c) atomicOr(&hflag[i >> 7], 1);
  }
  __syncthreads();
  for (int i = tid; i < npanel; i += 256) flags[i] = hflag[i];
  for (int i = tid; i < NSLOTS + 1; i += 256) misc[i] = 0.f;
}

// ---------- main: direct-register GEMM + symmetric masked-reduction ----------
// NO LDS staging of A/B (fb is 4MB -> L2-resident; K only 8 chunks; guide
// lesson #7: don't stage what cache-fits). Each wave loads its MFMA fragments
// global->VGPR directly; no barriers, no vmcnt choreography -> occupancy is
// VGPR-bound (~12-16 waves/CU) and TLP hides latency. Lower-triangle 1D grid.
// Per element both orientations folded (o1 row r col c; o2 mirrored, skipped
// on diagonal). MFMA sim(r,c)==sim(c,r) bit-exact.
__global__ __launch_bounds__(256) void simloss_kernel(
    const ushort* __restrict__ fb, const int2* __restrict__ metaG,
    const int* __restrict__ flags, float* __restrict__ misc,
    int d, int n_new, float alpha) {
  __shared__ int2 metaR[BM];
  __shared__ int2 metaC[BN];
  __shared__ float red[4];

  // linear lower-triangle index -> (by, bx), bx <= by
  const int l = blockIdx.x;
  int by = (int)((sqrtf(8.f * (float)l + 1.f) - 1.f) * 0.5f);
  while ((by + 1) * (by + 2) / 2 <= l) by++;
  while (by * (by + 1) / 2 > l) by--;
  const int bx = l - by * (by + 1) / 2;

  const int rowBase = by * BM;
  const int colBase = bx * BN;
  // skip when BOTH orientations are provably zero
  if ((rowBase >= n_new && flags[bx] == 0) &&
      (colBase >= n_new && flags[by] == 0)) return;

  const int tid  = threadIdx.x;
  const int lane = tid & 63;
  const int wid  = tid >> 6;        // 4 waves, 2x2 grid of 64x64 wave tiles
  const int wr   = wid >> 1;
  const int wc   = wid & 1;
  const int l15  = lane & 15;
  const int kb   = lane >> 4;

  if (tid < BM)        metaR[tid]       = metaG[rowBase + tid];
  else if (tid < 256)  metaC[tid - 128] = metaG[colBase + (tid - 128)];
  __syncthreads();

  // per-lane fragment base pointers (row-strided direct loads; L1-friendly:
  // one wave touches 16 rows x 64B contiguous, later ks hit the same lines)
  const ushort* pA = fb + (size_t)(rowBase + wr * 64 + l15) * d + kb * 8;
  const ushort* pB = fb + (size_t)(colBase + wc * 64 + l15) * d + kb * 8;

  f32x4 acc[4][4] = {};
  const int nk = d >> 5;            // 32-wide k chunks (d=256 -> 8)
#pragma unroll 2
  for (int ks = 0; ks < nk; ++ks) {
    short8 afr[4], bfr[4];
#pragma unroll
    for (int m = 0; m < 4; ++m)
      afr[m] = *reinterpret_cast<const short8*>(pA + (size_t)m * 16 * d + ks * 32);
#pragma unroll
    for (int nf = 0; nf < 4; ++nf)
      bfr[nf] = *reinterpret_cast<const short8*>(pB + (size_t)nf * 16 * d + ks * 32);
    // swapped operands: acc row = rowBase+wr*64+m*16+l15 (lane-fixed),
    // col = colBase+wc*64+nf*16+kb*4+q
#pragma unroll
    for (int m = 0; m < 4; ++m)
#pragma unroll
      for (int nf = 0; nf < 4; ++nf)
        acc[m][nf] = __builtin_amdgcn_mfma_f32_16x16x32_bf16(bfr[nf], afr[m], acc[m][nf], 0, 0, 0);
  }

  // ---- epilogue: fold both orientations into one scalar (R7-verified) ----
  const float beta = 1.0f - alpha;
  const bool diag = (bx == by);
  int tcr[4][4]; float cwc[4][4]; bool cnr[4][4];
#pragma unroll
  for (int nf = 0; nf < 4; ++nf)
#pragma unroll
    for (int q = 0; q < 4; ++q) {
      int cl = wc * 64 + nf * 16 + kb * 4 + q;
      int2 mc = metaC[cl];
      tcr[nf][q] = mc.x;
      cwc[nf][q] = __int_as_float(mc.y);
      cnr[nf][q] = (colBase + cl) < n_new;
    }

  const int  stale_row = n_new - 1;
  const bool blk_stale = (stale_row >= rowBase) && (stale_row < rowBase + BM);
  const int  srl = stale_row - rowBase;

  float tot = 0.f;
#pragma unroll
  for (int m = 0; m < 4; ++m) {
    int rl = wr * 64 + m * 16 + l15;
    int r  = rowBase + rl;
    int2 mr = metaR[rl];
    int   tr  = mr.x;
    float cwr = __int_as_float(mr.y);
    bool rnew = (r < n_new);
    float acwr = alpha * cwr, bcwr = beta * cwr;
    float p = 0.f, ng = 0.f, t2 = 0.f;
#pragma unroll
    for (int nf = 0; nf < 4; ++nf)
#pragma unroll
      for (int q = 0; q < 4; ++q) {
        float s = acc[m][nf][q];
        bool same = (tr == tcr[nf][q]);
        bool gm = (s > MARGIN);
        bool lp = (s < POS_THR);
        if (rnew) {                       // o1: row r, col c, weight cnt[c]
          if (same && lp)  p  += cwc[nf][q] * (1.0f - s);
          if (!same && gm) ng += s;
        } else {
          if (!same && gm) ng += cwc[nf][q] * s;
        }
        if (cnr[nf][q]) {                 // o2: row c, col r, weight cnt[r]
          if (same && lp)  t2 += acwr * (1.0f - s);
          if (!same && gm) t2 += beta * s;
        } else {
          if (!same && gm) t2 += bcwr * s;
        }
      }
    // stale row pos partial (o1 path covers it fully; o2 candidates have cnt=0)
    if (blk_stale && wr == (srl >> 6) && m == ((srl >> 4) & 3)) {
      float pr = p;
      pr += __shfl_xor(pr, 16); pr += __shfl_xor(pr, 32);
      if (lane < 16 && rl == srl) atomicAdd(&misc[NSLOTS], pr);
    }
    tot += rnew ? fmaf(alpha, p, beta * ng) : beta * ng;
    if (!diag) tot += t2;
  }
#pragma unroll
  for (int off = 32; off; off >>= 1) tot += __shfl_xor(tot, off);
  if (lane == 0) red[wid] = tot;
  __syncthreads();
  if (tid == 0)
    atomicAdd(&misc[blockIdx.x & (NSLOTS - 1)], red[0] + red[1] + red[2] + red[3]);
}

// ---------- finalize: 64 threads, read 257 floats ----------
__global__ void finalize_kernel(const float* __restrict__ misc,
                                float* __restrict__ out, int n, int n_new,
                                float alpha) {
  int t = threadIdx.x;
  float c = misc[t] + misc[t + 64] + misc[t + 128] + misc[t + 192];
#pragma unroll
  for (int off = 32; off; off >>= 1) c += __shfl_xor(c, off);
  if (t == 0)
    out[0] = (c + (float)(n - n_new) * alpha * misc[NSLOTS]) / (float)n;
}

// ---------- launch ----------
extern "C" void kernel_launch(void* const* d_in, const int* in_sizes, int n_in,
                              void* d_out, int out_size, void* d_ws, size_t ws_size,
                              hipStream_t stream) {
  const float* feature = (const float*)d_in[0];
  const int*   target  = (const int*)d_in[1];
  const int*   new_idx = (const int*)d_in[2];

  const int n     = in_sizes[1];
  const int d     = in_sizes[0] / n;
  const int n_new = in_sizes[2];
  const int n_old = (n_in > 3) ? in_sizes[3] : 0;
  const float alpha = (n_old != 0) ? 0.9f : 0.5f;
  const int npanel = n / BN;
  const int nTiles = npanel * (npanel + 1) / 2;

  auto al = [](size_t x) { return (x + 255) & ~(size_t)255; };
  char* ws = (char*)d_ws;
  ushort* fb    = (ushort*)ws;
  size_t  off   = al((size_t)n * d * sizeof(ushort));
  int2*   metaG = (int2*)(ws + off);  off += al((size_t)n * sizeof(int2));
  int*    flags = (int*)(ws + off);   off += al((size_t)npanel * sizeof(int));
  float*  misc  = (float*)(ws + off);

  int total8 = (n * d) / 8;
  int convBlocks = (total8 + 255) / 256;
  prep_kernel<<<convBlocks + 1, 256, 0, stream>>>(feature, fb, target, new_idx,
                                                  metaG, flags, misc,
                                                  total8, n, npanel, n_new,
                                                  convBlocks);

  simloss_kernel<<<nTiles, 256, 0, stream>>>(fb, metaG, flags, misc,
                                             d, n_new, alpha);

  finalize_kernel<<<1, 64, 0, stream>>>(misc, (float*)d_out, n, n_new, alpha);
}

// Round 11
// 128.810 us; speedup vs baseline: 1.1652x; 1.1652x over previous
//
#include <hip/hip_runtime.h>
#include <hip/hip_bf16.h>
#include <stdint.h>

#define MARGIN   0.5f
#define POS_THR  (1.0f - 1e-5f)

typedef __attribute__((ext_vector_type(8))) short  short8;
typedef __attribute__((ext_vector_type(4))) float  f32x4;

#define BM 128
#define BN 128
#define BK 32
#define NPANEL_SHIFT 7   // BN = 128
#define NSLOTS 256       // misc[0..255] partial sums, misc[256] = stale pos
#define MAXN_HIST 8192   // LDS histogram capacity in prep

// ---------- helpers ----------
__device__ __forceinline__ ushort f2bf_rne(float x) {
  uint32_t u = __float_as_uint(x);
  u += 0x7fffu + ((u >> 16) & 1u);
  return (ushort)(u >> 16);
}

__device__ __forceinline__ void async_load16(const ushort* g, ushort* l) {
  // width-16 global->LDS DMA; LDS dest = wave-uniform base + lane*16B
  __builtin_amdgcn_global_load_lds(
      (__attribute__((address_space(1))) void*)(const_cast<ushort*>(g)),
      (__attribute__((address_space(3))) void*)(l),
      16, 0, 0);
}

// ---------- prep: convert + setup. ALL producer stores NONTEMPORAL ----------
// Theory (R10/R11): fb was left DIRTY in the producing XCD's L2; the 8 reader
// XCDs' misses then need a cross-XCD writeback/HBM round trip (16.6MB @
// ~300GB/s == the ~55us simloss floor seen in every LDS variant R2-R9).
// nt stores stream fb/cnt/flags/misc through to L3/HBM -> clean, L3-served.
// (ext-vector types only: __builtin_nontemporal_* rejects HIP_vector_type.)
__global__ void prep_kernel(const float* __restrict__ src, ushort* __restrict__ dst,
                            const int* __restrict__ target, const int* __restrict__ new_idx,
                            int* __restrict__ cnt, int* __restrict__ flags,
                            float* __restrict__ misc,
                            int total8, int n, int npanel, int n_new, int convBlocks) {
  const int tid = threadIdx.x;
  if ((int)blockIdx.x < convBlocks) {
    int i = blockIdx.x * blockDim.x + tid;
    if (i < total8) {
      const f32x4* s4 = reinterpret_cast<const f32x4*>(src);
      f32x4 a = __builtin_nontemporal_load(&s4[i * 2]);
      f32x4 b = __builtin_nontemporal_load(&s4[i * 2 + 1]);
      short8 o;
      o[0] = (short)f2bf_rne(a[0]); o[1] = (short)f2bf_rne(a[1]);
      o[2] = (short)f2bf_rne(a[2]); o[3] = (short)f2bf_rne(a[3]);
      o[4] = (short)f2bf_rne(b[0]); o[5] = (short)f2bf_rne(b[1]);
      o[6] = (short)f2bf_rne(b[2]); o[7] = (short)f2bf_rne(b[3]);
      __builtin_nontemporal_store(o, &reinterpret_cast<short8*>(dst)[i]);
    }
    return;
  }
  // ---- setup block (n <= MAXN_HIST) ----
  __shared__ int hcnt[MAXN_HIST];
  __shared__ int hflag[MAXN_HIST / BN];
  for (int i = tid; i < n; i += 256) hcnt[i] = 0;
  for (int i = tid; i < npanel; i += 256) hflag[i] = 0;
  __syncthreads();
  for (int i = tid; i < n_new; i += 256) atomicAdd(&hcnt[new_idx[i]], 1);
  __syncthreads();
  for (int i = tid; i < n; i += 256) {
    int c = hcnt[i];
    __builtin_nontemporal_store(c, &cnt[i]);
    if (c) atomicOr(&hflag[i >> NPANEL_SHIFT], 1);
  }
  __syncthreads();
  for (int i = tid; i < npanel; i += 256) __builtin_nontemporal_store(hflag[i], &flags[i]);
  for (int i = tid; i < NSLOTS + 1; i += 256) __builtin_nontemporal_store(0.f, &misc[i]);
}

// ---------- main fused GEMM + symmetric masked-reduction (R7 verbatim) ----------
// Lower-triangle blocks only (bx<=by): each sim element s(r,c) folded twice
// (o1 row r col c; o2 mirrored, skipped on diagonal). MFMA s(r,c)==s(c,r)
// bit-exact. K-loop = R4 measured-best: 3-buf ring, counted vmcnt(4), one raw
// s_barrier per kstep, pinned order, swizzled LDS (rule #21 both-sides).
__global__ __launch_bounds__(256) void simloss_kernel(
    const ushort* __restrict__ fb, const int* __restrict__ target,
    const int* __restrict__ cnt, const int* __restrict__ flags,
    float* __restrict__ misc, int d, int n_new, float alpha) {
  __shared__ __align__(16) ushort Als[3][BM * BK];
  __shared__ __align__(16) ushort Bls[3][BN * BK];
  __shared__ int   t_row[BM];
  __shared__ int   t_col[BN];
  __shared__ float cw_col[BN];
  __shared__ float cw_row[BM];
  __shared__ float red[4];

  const int bx = blockIdx.x, by = blockIdx.y;
  if (bx > by) return;                        // upper triangle: mirror handles it
  const int tid = threadIdx.x;
  const int rowBase = by * BM;
  const int colBase = bx * BN;
  const bool diag = (bx == by);

  // skip when BOTH orientations are provably zero
  if ((rowBase >= n_new && flags[bx] == 0) &&
      (colBase >= n_new && flags[by] == 0)) return;

  if (tid < BM) {
    t_row[tid]  = target[rowBase + tid];
    cw_row[tid] = (float)cnt[rowBase + tid];
  }
  if (tid < BN) {
    t_col[tid]  = target[colBase + tid];
    cw_col[tid] = (float)cnt[colBase + tid];
  }

  const int lane = tid & 63;
  const int wid  = tid >> 6;        // 4 waves, 2x2 grid of 64x64 wave tiles
  const int wr   = wid >> 1;
  const int wc   = wid & 1;
  const int l15  = lane & 15;
  const int kb   = lane >> 4;

  // staging: 512 16B-chunks per 128x32 tile; wave w issues chunks (2w+cc)*64+lane;
  // global source pre-swizzled with involution slot^=(row>>1)&3 (rule #21)
  const int ch0 = (wid * 2 + 0) * 64 + lane;
  const int ch1 = (wid * 2 + 1) * 64 + lane;
  const int r0 = ch0 >> 2, kq0 = (ch0 & 3) ^ ((ch0 >> 3) & 3);
  const int r1 = ch1 >> 2, kq1 = (ch1 & 3) ^ ((ch1 >> 3) & 3);
  const ushort* gA0 = fb + (size_t)(rowBase + r0) * d + kq0 * 8;
  const ushort* gA1 = fb + (size_t)(rowBase + r1) * d + kq1 * 8;
  const ushort* gB0 = fb + (size_t)(colBase + r0) * d + kq0 * 8;
  const ushort* gB1 = fb + (size_t)(colBase + r1) * d + kq1 * 8;
  const int lo0 = (wid * 2 + 0) * 512;
  const int lo1 = (wid * 2 + 1) * 512;

  f32x4 acc[4][4] = {};

  int aoff[4], boff[4];
#pragma unroll
  for (int m = 0; m < 4; ++m) {
    int row = wr * 64 + m * 16 + l15;
    aoff[m] = row * 32 + ((kb ^ ((row >> 1) & 3)) * 8);
  }
#pragma unroll
  for (int nf = 0; nf < 4; ++nf) {
    int row = wc * 64 + nf * 16 + l15;
    boff[nf] = row * 32 + ((kb ^ ((row >> 1) & 3)) * 8);
  }

  // drain metadata loads so manual vmcnt counts are exact
  asm volatile("s_waitcnt vmcnt(0) lgkmcnt(0)" ::: "memory");
  __builtin_amdgcn_sched_barrier(0);

  // prologue: stage tiles 0 and 1 (8 loads in flight)
  async_load16(gA0, &Als[0][lo0]);
  async_load16(gA1, &Als[0][lo1]);
  async_load16(gB0, &Bls[0][lo0]);
  async_load16(gB1, &Bls[0][lo1]);
  const int nk = d / BK;
  if (nk > 1) {
    async_load16(gA0 + BK, &Als[1][lo0]);
    async_load16(gA1 + BK, &Als[1][lo1]);
    async_load16(gB0 + BK, &Bls[1][lo0]);
    async_load16(gB1 + BK, &Bls[1][lo1]);
  }

  int cur = 0;
  for (int t = 0; t < nk; ++t) {
    if (t == nk - 1) asm volatile("s_waitcnt vmcnt(0)" ::: "memory");
    else             asm volatile("s_waitcnt vmcnt(4)" ::: "memory");
    __builtin_amdgcn_s_barrier();
    __builtin_amdgcn_sched_barrier(0);

    if (t + 2 < nk) {
      int nxt = cur + 2; if (nxt >= 3) nxt -= 3;
      int ko = (t + 2) * BK;
      async_load16(gA0 + ko, &Als[nxt][lo0]);
      async_load16(gA1 + ko, &Als[nxt][lo1]);
      async_load16(gB0 + ko, &Bls[nxt][lo0]);
      async_load16(gB1 + ko, &Bls[nxt][lo1]);
    }

    short8 afr[4], bfr[4];
#pragma unroll
    for (int m = 0; m < 4; ++m)
      afr[m] = *reinterpret_cast<const short8*>(&Als[cur][aoff[m]]);
#pragma unroll
    for (int nf = 0; nf < 4; ++nf)
      bfr[nf] = *reinterpret_cast<const short8*>(&Bls[cur][boff[nf]]);
    asm volatile("s_waitcnt lgkmcnt(0)" ::: "memory");
    __builtin_amdgcn_sched_barrier(0);

    // swapped operands: acc row = rowBase+wr*64+m*16+l15 (lane-fixed),
    // col = colBase+wc*64+nf*16+kb*4+q
#pragma unroll
    for (int m = 0; m < 4; ++m)
#pragma unroll
      for (int nf = 0; nf < 4; ++nf)
        acc[m][nf] = __builtin_amdgcn_mfma_f32_16x16x32_bf16(bfr[nf], afr[m], acc[m][nf], 0, 0, 0);

    cur = (cur + 1 == 3) ? 0 : cur + 1;
  }

  // ---- epilogue: fold both orientations into one scalar ----
  const float beta = 1.0f - alpha;
  int tc_r[4][4]; float cw_c[4][4]; bool cn_r[4][4];
#pragma unroll
  for (int nf = 0; nf < 4; ++nf)
#pragma unroll
    for (int q = 0; q < 4; ++q) {
      int cl = wc * 64 + nf * 16 + kb * 4 + q;
      tc_r[nf][q] = t_col[cl];
      cw_c[nf][q] = cw_col[cl];
      cn_r[nf][q] = (colBase + cl) < n_new;
    }

  const int  stale_row = n_new - 1;
  const bool blk_stale = (stale_row >= rowBase) && (stale_row < rowBase + BM);
  const int  srl = stale_row - rowBase;

  float tot = 0.f;
#pragma unroll
  for (int m = 0; m < 4; ++m) {
    int rl = wr * 64 + m * 16 + l15;
    int r  = rowBase + rl;
    int tr = t_row[rl];
    bool rnew = (r < n_new);
    float cwr  = cw_row[rl];
    float acwr = alpha * cwr;
    float bcwr = beta * cwr;
    float p = 0.f, ng = 0.f, t2 = 0.f;
#pragma unroll
    for (int nf = 0; nf < 4; ++nf)
#pragma unroll
      for (int q = 0; q < 4; ++q) {
        float s = acc[m][nf][q];
        bool same = (tr == tc_r[nf][q]);
        bool gm = (s > MARGIN);
        bool lp = (s < POS_THR);
        // o1: row r, col c, weight cnt[c]
        if (rnew) {
          if (same && lp) p  += cw_c[nf][q] * (1.0f - s);
          if (!same && gm) ng += s;
        } else {
          if (!same && gm) ng += cw_c[nf][q] * s;
        }
        // o2: row c, col r, weight cnt[r] (discarded on diag)
        if (cn_r[nf][q]) {
          if (same && lp)  t2 += acwr * (1.0f - s);
          if (!same && gm) t2 += beta * s;
        } else {
          if (!same && gm) t2 += bcwr * s;
        }
      }
    // stale row pos partial (o1 path covers it fully: o2 candidates have cnt=0)
    if (blk_stale && wr == (srl >> 6) && m == ((srl >> 4) & 3)) {
      float pr = p;
      pr += __shfl_xor(pr, 16); pr += __shfl_xor(pr, 32);
      if (lane < 16 && rl == srl) atomicAdd(&misc[NSLOTS], pr);
    }
    tot += rnew ? fmaf(alpha, p, beta * ng) : beta * ng;
    if (!diag) tot += t2;
  }
#pragma unroll
  for (int off = 32; off; off >>= 1) tot += __shfl_xor(tot, off);
  if (lane == 0) red[wid] = tot;
  __syncthreads();
  if (tid == 0)
    atomicAdd(&misc[(by * gridDim.x + bx) & (NSLOTS - 1)],
              red[0] + red[1] + red[2] + red[3]);
}

// ---------- finalize: 64 threads, read 257 floats ----------
__global__ void finalize_kernel(const float* __restrict__ misc,
                                float* __restrict__ out, int n, int n_new,
                                float alpha) {
  int t = threadIdx.x;
  float c = misc[t] + misc[t + 64] + misc[t + 128] + misc[t + 192];
#pragma unroll
  for (int off = 32; off; off >>= 1) c += __shfl_xor(c, off);
  if (t == 0)
    out[0] = (c + (float)(n - n_new) * alpha * misc[NSLOTS]) / (float)n;
}

// ---------- launch ----------
extern "C" void kernel_launch(void* const* d_in, const int* in_sizes, int n_in,
                              void* d_out, int out_size, void* d_ws, size_t ws_size,
                              hipStream_t stream) {
  const float* feature = (const float*)d_in[0];
  const int*   target  = (const int*)d_in[1];
  const int*   new_idx = (const int*)d_in[2];

  const int n     = in_sizes[1];
  const int d     = in_sizes[0] / n;
  const int n_new = in_sizes[2];
  const int n_old = (n_in > 3) ? in_sizes[3] : 0;
  const float alpha = (n_old != 0) ? 0.9f : 0.5f;
  const int npanel = n / BN;

  auto al = [](size_t x) { return (x + 255) & ~(size_t)255; };
  char* ws = (char*)d_ws;
  ushort* fb    = (ushort*)ws;
  size_t  off   = al((size_t)n * d * sizeof(ushort));
  int*    cnt   = (int*)(ws + off);   off += al((size_t)n * sizeof(int));
  int*    flags = (int*)(ws + off);   off += al((size_t)npanel * sizeof(int));
  float*  misc  = (float*)(ws + off);

  int total8 = (n * d) / 8;
  int convBlocks = (total8 + 255) / 256;
  prep_kernel<<<convBlocks + 1, 256, 0, stream>>>(feature, fb, target, new_idx,
                                                  cnt, flags, misc,
                                                  total8, n, npanel, n_new,
                                                  convBlocks);

  dim3 grid(n / BN, n / BM);
  simloss_kernel<<<grid, 256, 0, stream>>>(fb, target, cnt, flags, misc,
                                           d, n_new, alpha);

  finalize_kernel<<<1, 64, 0, stream>>>(misc, (float*)d_out, n, n_new, alpha);
}